// Round 1
// baseline (15058.925 us; speedup 1.0000x reference)
//
#include <hip/hip_runtime.h>

#define N_POINTS    100000
#define N_KEYPOINTS 16384
#define N_PAIRS     524288
#define D_OUT       300
#define JC          20    // layer-4 column chunk (divides 300)
#define TR          32    // output-MLP row tile

// ---------------------------------------------------------------------------
// Kernel 1: fused gather + 4-layer point MLP + atomic scatter-max into agg.
// One thread per pair. Activations live in registers (all activation-array
// indices are compile-time via full unrolling). Weight reads use wave-uniform
// addresses -> scalar loads (broadcast), so weight bandwidth is per-wave.
// ---------------------------------------------------------------------------
__global__ __launch_bounds__(256, 2) void point_mlp_scatter(
    const float* __restrict__ features,     // [N_POINTS,1]
    const float* __restrict__ coords,       // [N_POINTS,3]
    const int*   __restrict__ keypoints,    // [N_KEYPOINTS,1]
    const int*   __restrict__ set_indices,  // [2,N_PAIRS]
    const float* __restrict__ pw1, const float* __restrict__ pb1,  // [4,32],[32]
    const float* __restrict__ pw2, const float* __restrict__ pb2,  // [32,64],[64]
    const float* __restrict__ pw3, const float* __restrict__ pb3,  // [64,128],[128]
    const float* __restrict__ pw4, const float* __restrict__ pb4,  // [128,300],[300]
    float* __restrict__ agg)                // [N_KEYPOINTS,300], pre-zeroed
{
    const int s = blockIdx.x * 256 + threadIdx.x;
    if (s >= N_PAIRS) return;

    const int pt = set_indices[s];
    const int st = set_indices[N_PAIRS + s];
    const int kp = keypoints[st];

    float x0[4];
    x0[0] = features[pt];
    x0[1] = coords[pt * 3 + 0] - coords[kp * 3 + 0];
    x0[2] = coords[pt * 3 + 1] - coords[kp * 3 + 1];
    x0[3] = coords[pt * 3 + 2] - coords[kp * 3 + 2];

    // Layer 1: 4 -> 32
    float x1[32];
#pragma unroll
    for (int j = 0; j < 32; ++j) {
        float a = pb1[j];
#pragma unroll
        for (int k = 0; k < 4; ++k) a = fmaf(x0[k], pw1[k * 32 + j], a);
        x1[j] = fmaxf(a, 0.f);
    }

    // Layer 2: 32 -> 64
    float x2[64];
#pragma unroll
    for (int j = 0; j < 64; ++j) {
        float a = pb2[j];
#pragma unroll
        for (int k = 0; k < 32; ++k) a = fmaf(x1[k], pw2[k * 64 + j], a);
        x2[j] = fmaxf(a, 0.f);
    }

    // Layer 3: 64 -> 128
    float x3[128];
#pragma unroll
    for (int j = 0; j < 128; ++j) {
        float a = pb3[j];
#pragma unroll
        for (int k = 0; k < 64; ++k) a = fmaf(x2[k], pw3[k * 128 + j], a);
        x3[j] = fmaxf(a, 0.f);
    }

    // Layer 4: 128 -> 300, chunked by JC columns, fused scatter-max.
    int* aggi = (int*)agg;
    const long base = (long)st * D_OUT;
    for (int jb = 0; jb < D_OUT; jb += JC) {
        float acc[JC];
#pragma unroll
        for (int jj = 0; jj < JC; ++jj) acc[jj] = pb4[jb + jj];
#pragma unroll
        for (int k = 0; k < 128; ++k) {
            const float xk = x3[k];
#pragma unroll
            for (int jj = 0; jj < JC; ++jj)
                acc[jj] = fmaf(xk, pw4[k * D_OUT + jb + jj], acc[jj]);
        }
#pragma unroll
        for (int jj = 0; jj < JC; ++jj) {
            const float v = acc[jj];
            // agg is zero-initialized; nonneg floats compare correctly as ints.
            if (v > 0.f) atomicMax(&aggi[base + jb + jj], __float_as_int(v));
        }
    }
}

// ---------------------------------------------------------------------------
// Kernel 2: output MLP, 2 layers fused per 32-row tile.
// 320 threads: thread t owns output column t (t < 300). A-tile and hidden
// tile staged in LDS; weight loads coalesced; LDS reads are broadcasts.
// ---------------------------------------------------------------------------
__global__ __launch_bounds__(320, 2) void out_mlp(
    const float* __restrict__ agg,  // [N_KEYPOINTS,300] (already >= 0)
    const float* __restrict__ ow1, const float* __restrict__ ob1,  // [300,300],[300]
    const float* __restrict__ ow2, const float* __restrict__ ob2,  // [300,300],[300]
    float* __restrict__ y)          // [N_KEYPOINTS,300]
{
    __shared__ float A[TR * D_OUT];
    __shared__ float H[TR * D_OUT];
    const int t = threadIdx.x;
    const long rb = (long)blockIdx.x * TR;

    for (int l = t; l < TR * D_OUT; l += 320) A[l] = agg[rb * D_OUT + l];
    __syncthreads();

    if (t < D_OUT) {
        float acc[TR];
#pragma unroll
        for (int r = 0; r < TR; ++r) acc[r] = ob1[t];
        for (int k = 0; k < D_OUT; k += 4) {
            const float w0 = ow1[(k + 0) * D_OUT + t];
            const float w1 = ow1[(k + 1) * D_OUT + t];
            const float w2 = ow1[(k + 2) * D_OUT + t];
            const float w3 = ow1[(k + 3) * D_OUT + t];
#pragma unroll
            for (int r = 0; r < TR; ++r) {
                const float4 a4 = *reinterpret_cast<const float4*>(&A[r * D_OUT + k]);
                acc[r] = fmaf(a4.x, w0, acc[r]);
                acc[r] = fmaf(a4.y, w1, acc[r]);
                acc[r] = fmaf(a4.z, w2, acc[r]);
                acc[r] = fmaf(a4.w, w3, acc[r]);
            }
        }
#pragma unroll
        for (int r = 0; r < TR; ++r) H[r * D_OUT + t] = fmaxf(acc[r], 0.f);
    }
    __syncthreads();

    if (t < D_OUT) {
        float acc[TR];
#pragma unroll
        for (int r = 0; r < TR; ++r) acc[r] = ob2[t];
        for (int k = 0; k < D_OUT; k += 4) {
            const float w0 = ow2[(k + 0) * D_OUT + t];
            const float w1 = ow2[(k + 1) * D_OUT + t];
            const float w2 = ow2[(k + 2) * D_OUT + t];
            const float w3 = ow2[(k + 3) * D_OUT + t];
#pragma unroll
            for (int r = 0; r < TR; ++r) {
                const float4 h4 = *reinterpret_cast<const float4*>(&H[r * D_OUT + k]);
                acc[r] = fmaf(h4.x, w0, acc[r]);
                acc[r] = fmaf(h4.y, w1, acc[r]);
                acc[r] = fmaf(h4.z, w2, acc[r]);
                acc[r] = fmaf(h4.w, w3, acc[r]);
            }
        }
#pragma unroll
        for (int r = 0; r < TR; ++r) y[(rb + r) * D_OUT + t] = fmaxf(acc[r], 0.f);
    }
}

extern "C" void kernel_launch(void* const* d_in, const int* in_sizes, int n_in,
                              void* d_out, int out_size, void* d_ws, size_t ws_size,
                              hipStream_t stream) {
    const float* features    = (const float*)d_in[0];
    const float* coords      = (const float*)d_in[1];
    const int*   keypoints   = (const int*)d_in[2];
    const int*   set_indices = (const int*)d_in[3];
    const float* pw1 = (const float*)d_in[4];
    const float* pb1 = (const float*)d_in[5];
    const float* pw2 = (const float*)d_in[6];
    const float* pb2 = (const float*)d_in[7];
    const float* pw3 = (const float*)d_in[8];
    const float* pb3 = (const float*)d_in[9];
    const float* pw4 = (const float*)d_in[10];
    const float* pb4 = (const float*)d_in[11];
    const float* ow1 = (const float*)d_in[12];
    const float* ob1 = (const float*)d_in[13];
    const float* ow2 = (const float*)d_in[14];
    const float* ob2 = (const float*)d_in[15];

    float* agg = (float*)d_ws;                       // 16384*300*4 = 19.66 MB
    float* y   = (float*)d_out;

    hipMemsetAsync(agg, 0, (size_t)N_KEYPOINTS * D_OUT * sizeof(float), stream);

    point_mlp_scatter<<<N_PAIRS / 256, 256, 0, stream>>>(
        features, coords, keypoints, set_indices,
        pw1, pb1, pw2, pb2, pw3, pb3, pw4, pb4, agg);

    out_mlp<<<N_KEYPOINTS / TR, 320, 0, stream>>>(agg, ow1, ob1, ow2, ob2, y);
}